// Round 3
// baseline (766.898 us; speedup 1.0000x reference)
//
#include <hip/hip_runtime.h>

typedef __attribute__((ext_vector_type(8))) short short8;
typedef __attribute__((ext_vector_type(4))) float f32x4;
typedef unsigned short u16;
typedef unsigned int u32;
typedef __attribute__((ext_vector_type(4))) unsigned int u32x4;

union pk8 { u32x4 u; short8 s; };

#define BLOCK 384
#define WPB 6
#define GRID 512
#define KP 136   // padded LDS row stride (shorts); 16B-aligned rows, b128 reads at the 8-cycle floor

__device__ __forceinline__ float tanh_fast(float x) {
    float e = __expf(2.0f * x);
    return 1.0f - 2.0f / (e + 1.0f);   // exact at +-inf
}
__device__ __forceinline__ u16 f2bf(float f) {   // RNE (weights staging, once)
    u32 u = __float_as_uint(f);
    return (u16)((u + 0x7fffu + ((u >> 16) & 1u)) >> 16);
}
__device__ __forceinline__ u32 pkbf(float a, float b) {  // round-half-up pack: a->low, b->high
    u32 ua = (__float_as_uint(a) + 0x8000u) >> 16;
    u32 ub = (__float_as_uint(b) + 0x8000u) & 0xffff0000u;
    return ub | ua;
}
#define MFMA16(acc, a, b) acc = __builtin_amdgcn_mfma_f32_16x16x32_bf16(a, b, acc, 0, 0, 0)

__global__ __launch_bounds__(BLOCK, 3) void pinn_mfma3(
    const float* __restrict__ x,
    const float* __restrict__ W1, const float* __restrict__ b1,
    const float* __restrict__ W2, const float* __restrict__ b2,
    const float* __restrict__ W3, const float* __restrict__ b3,
    const float* __restrict__ W4, const float* __restrict__ b4,
    float* __restrict__ out, int N)
{
    // weights only: 55.3 KB -> 2 blocks/CU
    __shared__ __align__(16) u16 w2t[128 * KP];    // W2^T: [n][k]
    __shared__ __align__(16) u16 w3t[64 * KP];     // W3^T: [n][k]
    __shared__ __align__(16) float4 w1s[128];      // q-transposed: slot kf*32+j*4+q holds feature kf*32+q*8+j
    __shared__ __align__(16) float b2s[128];
    __shared__ __align__(16) float b3s[64];
    __shared__ __align__(16) float w4s[64];

    for (int i = threadIdx.x; i < 128 * 128; i += BLOCK) {
        int k = i >> 7, n = i & 127;
        w2t[n * KP + k] = f2bf(W2[i]);
    }
    for (int i = threadIdx.x; i < 128 * 64; i += BLOCK) {
        int k = i >> 6, n = i & 63;
        w3t[n * KP + k] = f2bf(W3[i]);
    }
    for (int i = threadIdx.x; i < 128; i += BLOCK) {
        int kf = i >> 5, j = (i >> 2) & 7, qq = i & 3;
        int f = kf * 32 + qq * 8 + j;
        w1s[i] = make_float4(W1[f], W1[128 + f], W1[256 + f], b1[f]);
        b2s[i] = b2[i];
    }
    for (int i = threadIdx.x; i < 64; i += BLOCK) { b3s[i] = b3[i]; w4s[i] = W4[i]; }
    __syncthreads();

    const int lane = threadIdx.x & 63;
    const int wv = threadIdx.x >> 6;
    const int q = lane >> 4;       // k-quad for A/B frags
    const int e = lane & 15;       // example column
    const int srcA = (((q * 2) & 3) << 4) | e;       // transform source lanes (nt-independent)
    const int srcB = (((q * 2 + 1) & 3) << 4) | e;
    const int hiHalf = q >> 1;
    const float b4v = b4[0];

    const int ntiles = N >> 4;
    const int gw = blockIdx.x * WPB + wv;
    const int nw = GRID * WPB;

    for (int tile = gw; tile < ntiles; tile += nw) {
        const int gbase = tile << 4;
        const float* xp = x + 3 * (size_t)(gbase + e);
        float x0 = xp[0], x1 = xp[1], x2 = xp[2];

        // ===== layer 1 (3 -> 128): produce B2 frags directly in registers =====
        // B2f[s][kf] element j = stream-s activation of feature kf*32+q*8+j, example e
        pk8 B2f[4][4];
#pragma unroll
        for (int kf = 0; kf < 4; kf++) {
#pragma unroll
            for (int jp = 0; jp < 4; jp++) {
                float hv[2], av_[2], tv[2], cv[2];
#pragma unroll
                for (int u = 0; u < 2; u++) {
                    float4 w = w1s[kf * 32 + (jp * 2 + u) * 4 + q];  // {W1[0][f],W1[1][f],W1[2][f],b1[f]}
                    float z = fmaf(x0, w.x, fmaf(x1, w.y, fmaf(x2, w.z, w.w)));
                    float h = tanh_fast(z);
                    float g = 1.0f - h * h;
                    hv[u] = h;
                    av_[u] = g * w.x;
                    tv[u] = g * w.y;
                    cv[u] = -2.0f * h * g * w.x * w.x;
                }
                B2f[0][kf].u[jp] = pkbf(hv[0], hv[1]);
                B2f[1][kf].u[jp] = pkbf(av_[0], av_[1]);
                B2f[2][kf].u[jp] = pkbf(tv[0], tv[1]);
                B2f[3][kf].u[jp] = pkbf(cv[0], cv[1]);
            }
        }

        // ===== layer 2 (128 -> 128): A=W2^T from LDS, B=activations; epilogue shuffles into B3 frags =====
        pk8 B3f[4][4];
#pragma unroll
        for (int nt = 0; nt < 8; nt++) {
            const u16* arow = &w2t[(nt * 16 + e) * KP];
            f32x4 bia = *(const f32x4*)&b2s[nt * 16 + q * 4];
            f32x4 av = bia;
            f32x4 aa = {0.f, 0.f, 0.f, 0.f};
            f32x4 at_ = {0.f, 0.f, 0.f, 0.f};
            f32x4 ac = {0.f, 0.f, 0.f, 0.f};
#pragma unroll
            for (int kf = 0; kf < 4; kf++) {
                short8 A = *(const short8*)&arow[kf * 32 + q * 8];
                MFMA16(av, A, B2f[0][kf].s);
                MFMA16(aa, A, B2f[1][kf].s);
                MFMA16(at_, A, B2f[2][kf].s);
                MFMA16(ac, A, B2f[3][kf].s);
            }
            // chain rule in C-layout (rows = features nt*16+q*4+r, col = example e)
            float h_[4], na_[4], nv_[4], nc_[4];
#pragma unroll
            for (int r = 0; r < 4; r++) {
                float h = tanh_fast(av[r]);
                float g = 1.0f - h * h;
                h_[r] = h;
                na_[r] = g * aa[r];
                nv_[r] = g * at_[r];
                nc_[r] = g * ac[r] - 2.0f * h * g * aa[r] * aa[r];
            }
            u32 lo0 = pkbf(h_[0], h_[1]), hi0 = pkbf(h_[2], h_[3]);
            u32 lo1 = pkbf(na_[0], na_[1]), hi1 = pkbf(na_[2], na_[3]);
            u32 lo2 = pkbf(nv_[0], nv_[1]), hi2 = pkbf(nv_[2], nv_[3]);
            u32 lo3 = pkbf(nc_[0], nc_[1]), hi3 = pkbf(nc_[2], nc_[3]);
            // cross-lane transform: C-layout -> next-layer B-frag (same example column)
            u32 lA0 = (u32)__shfl((int)lo0, srcA), hA0 = (u32)__shfl((int)hi0, srcA);
            u32 lB0 = (u32)__shfl((int)lo0, srcB), hB0 = (u32)__shfl((int)hi0, srcB);
            u32 lA1 = (u32)__shfl((int)lo1, srcA), hA1 = (u32)__shfl((int)hi1, srcA);
            u32 lB1 = (u32)__shfl((int)lo1, srcB), hB1 = (u32)__shfl((int)hi1, srcB);
            u32 lA2 = (u32)__shfl((int)lo2, srcA), hA2 = (u32)__shfl((int)hi2, srcA);
            u32 lB2 = (u32)__shfl((int)lo2, srcB), hB2 = (u32)__shfl((int)hi2, srcB);
            u32 lA3 = (u32)__shfl((int)lo3, srcA), hA3 = (u32)__shfl((int)hi3, srcA);
            u32 lB3 = (u32)__shfl((int)lo3, srcB), hB3 = (u32)__shfl((int)hi3, srcB);
            if (hiHalf == (nt & 1)) {
                const int kf = nt >> 1;
                B3f[0][kf].u[0] = lA0; B3f[0][kf].u[1] = hA0; B3f[0][kf].u[2] = lB0; B3f[0][kf].u[3] = hB0;
                B3f[1][kf].u[0] = lA1; B3f[1][kf].u[1] = hA1; B3f[1][kf].u[2] = lB1; B3f[1][kf].u[3] = hB1;
                B3f[2][kf].u[0] = lA2; B3f[2][kf].u[1] = hA2; B3f[2][kf].u[2] = lB2; B3f[2][kf].u[3] = hB2;
                B3f[3][kf].u[0] = lA3; B3f[3][kf].u[1] = hA3; B3f[3][kf].u[2] = lB3; B3f[3][kf].u[3] = hB3;
            }
        }

        // ===== layer 3 (128 -> 64) + layer 4 (64 -> 1), fused =====
        float sT = 0.f, sA = 0.f, sTt = 0.f, sC = 0.f;
#pragma unroll
        for (int nt3 = 0; nt3 < 4; nt3++) {
            const u16* arow = &w3t[(nt3 * 16 + e) * KP];
            f32x4 bia = *(const f32x4*)&b3s[nt3 * 16 + q * 4];
            f32x4 v3 = bia;
            f32x4 a3 = {0.f, 0.f, 0.f, 0.f};
            f32x4 t3 = {0.f, 0.f, 0.f, 0.f};
            f32x4 c3 = {0.f, 0.f, 0.f, 0.f};
#pragma unroll
            for (int kf = 0; kf < 4; kf++) {
                short8 A = *(const short8*)&arow[kf * 32 + q * 8];
                MFMA16(v3, A, B3f[0][kf].s);
                MFMA16(a3, A, B3f[1][kf].s);
                MFMA16(t3, A, B3f[2][kf].s);
                MFMA16(c3, A, B3f[3][kf].s);
            }
            f32x4 w4v = *(const f32x4*)&w4s[nt3 * 16 + q * 4];
#pragma unroll
            for (int r = 0; r < 4; r++) {
                float h = tanh_fast(v3[r]);
                float g = 1.0f - h * h;
                float wr = w4v[r];
                sT = fmaf(h, wr, sT);
                sA = fmaf(g * a3[r], wr, sA);
                sTt = fmaf(g * t3[r], wr, sTt);
                sC = fmaf(g * c3[r] - 2.0f * h * g * a3[r] * a3[r], wr, sC);
            }
        }
        // reduce across the 4 q-groups (features are q-distributed)
        sT += __shfl_xor(sT, 16);  sT += __shfl_xor(sT, 32);
        sA += __shfl_xor(sA, 16);  sA += __shfl_xor(sA, 32);
        sTt += __shfl_xor(sTt, 16); sTt += __shfl_xor(sTt, 32);
        sC += __shfl_xor(sC, 16);  sC += __shfl_xor(sC, 32);

        if (lane < 16) {
            *(float4*)(out + 4 * (size_t)(gbase + lane)) =
                make_float4(sT + b4v, sA, sTt, sC);
        }
    }
}

extern "C" void kernel_launch(void* const* d_in, const int* in_sizes, int n_in,
                              void* d_out, int out_size, void* d_ws, size_t ws_size,
                              hipStream_t stream) {
    const float* x  = (const float*)d_in[0];
    const float* W1 = (const float*)d_in[1];
    const float* b1 = (const float*)d_in[2];
    const float* W2 = (const float*)d_in[3];
    const float* b2 = (const float*)d_in[4];
    const float* W3 = (const float*)d_in[5];
    const float* b3 = (const float*)d_in[6];
    const float* W4 = (const float*)d_in[7];
    const float* b4 = (const float*)d_in[8];
    float* out = (float*)d_out;
    int N = in_sizes[0] / 3;

    hipLaunchKernelGGL(pinn_mfma3, dim3(GRID), dim3(BLOCK), 0, stream,
                       x, W1, b1, W2, b2, W3, b3, W4, b4, out, N);
}

// Round 4
// 556.212 us; speedup vs baseline: 1.3788x; 1.3788x over previous
//
#include <hip/hip_runtime.h>

typedef __attribute__((ext_vector_type(8))) short short8;
typedef __attribute__((ext_vector_type(4))) float f32x4;
typedef __attribute__((ext_vector_type(4))) unsigned int u32x4;
typedef unsigned short u16;
typedef unsigned int u32;

#define BLOCK 256
#define WPB 4
#define GRID 512
#define KP 136   // padded LDS row stride (shorts)

__device__ __forceinline__ float tanh_fast(float x) {
    float e = __expf(2.0f * x);
    return 1.0f - 2.0f / (e + 1.0f);   // exact at +-inf
}
__device__ __forceinline__ u16 f2bf(float f) {   // RNE (weights staging, once)
    u32 u = __float_as_uint(f);
    return (u16)((u + 0x7fffu + ((u >> 16) & 1u)) >> 16);
}
__device__ __forceinline__ u32 pkbf(float a, float b) {  // round-half-up pack: a->low, b->high
    u32 ua = (__float_as_uint(a) + 0x8000u) >> 16;
    u32 ub = (__float_as_uint(b) + 0x8000u) & 0xffff0000u;
    return ub | ua;
}
#define MFMA16(acc, a, b) acc = __builtin_amdgcn_mfma_f32_16x16x32_bf16(a, b, acc, 0, 0, 0)
#define AS_S8(v) __builtin_bit_cast(short8, v)

__global__ __launch_bounds__(BLOCK, 2) void pinn_mfma4(
    const float* __restrict__ x,
    const float* __restrict__ W1, const float* __restrict__ b1,
    const float* __restrict__ W2, const float* __restrict__ b2,
    const float* __restrict__ W3, const float* __restrict__ b3,
    const float* __restrict__ W4, const float* __restrict__ b4,
    float* __restrict__ out, int N)
{
    // weights only: 55.3 KB -> 2 blocks/CU
    __shared__ __align__(16) u16 w2t[128 * KP];    // W2^T: [n][k]
    __shared__ __align__(16) u16 w3t[64 * KP];     // W3^T: [n][k]
    __shared__ __align__(16) float4 w1s[128];      // q-transposed: slot kf*32+j*4+q holds feature kf*32+q*8+j
    __shared__ __align__(16) float b2s[128];
    __shared__ __align__(16) float b3s[64];
    __shared__ __align__(16) float w4s[64];

    for (int i = threadIdx.x; i < 128 * 128; i += BLOCK) {
        int k = i >> 7, n = i & 127;
        w2t[n * KP + k] = f2bf(W2[i]);
    }
    for (int i = threadIdx.x; i < 128 * 64; i += BLOCK) {
        int k = i >> 6, n = i & 63;
        w3t[n * KP + k] = f2bf(W3[i]);
    }
    for (int i = threadIdx.x; i < 128; i += BLOCK) {
        int kf = i >> 5, j = (i >> 2) & 7, qq = i & 3;
        int f = kf * 32 + qq * 8 + j;
        w1s[i] = make_float4(W1[f], W1[128 + f], W1[256 + f], b1[f]);
        b2s[i] = b2[i];
    }
    for (int i = threadIdx.x; i < 64; i += BLOCK) { b3s[i] = b3[i]; w4s[i] = W4[i]; }
    __syncthreads();

    const int lane = threadIdx.x & 63;
    const int wv = threadIdx.x >> 6;
    const int q = lane >> 4;       // k-quad for A/B frags
    const int e = lane & 15;       // example column
    const int srcA = (((q * 2) & 3) << 4) | e;       // transform source lanes (nt-independent)
    const int srcB = (((q * 2 + 1) & 3) << 4) | e;
    const int hiHalf = q >> 1;
    const float b4v = b4[0];

    const int ntiles = N >> 4;
    const int gw = blockIdx.x * WPB + wv;
    const int nw = GRID * WPB;

    for (int tile = gw; tile < ntiles; tile += nw) {
        const int gbase = tile << 4;
        const float* xp = x + 3 * (size_t)(gbase + e);
        float x0 = xp[0], x1 = xp[1], x2 = xp[2];

        // ===== layer 1 (3 -> 128): produce B2 frags directly in registers =====
        u32x4 B2f[4][4];   // [stream][kf]
#pragma unroll
        for (int kf = 0; kf < 4; kf++) {
            u32x4 fv, fa, ft, fc;
#pragma unroll
            for (int jp = 0; jp < 4; jp++) {
                float hv[2], av_[2], tv[2], cv[2];
#pragma unroll
                for (int u = 0; u < 2; u++) {
                    float4 w = w1s[kf * 32 + (jp * 2 + u) * 4 + q];  // {W1[0][f],W1[1][f],W1[2][f],b1[f]}
                    float z = fmaf(x0, w.x, fmaf(x1, w.y, fmaf(x2, w.z, w.w)));
                    float h = tanh_fast(z);
                    float g = 1.0f - h * h;
                    hv[u] = h;
                    av_[u] = g * w.x;
                    tv[u] = g * w.y;
                    cv[u] = -2.0f * h * g * w.x * w.x;
                }
                fv[jp] = pkbf(hv[0], hv[1]);
                fa[jp] = pkbf(av_[0], av_[1]);
                ft[jp] = pkbf(tv[0], tv[1]);
                fc[jp] = pkbf(cv[0], cv[1]);
            }
            B2f[0][kf] = fv; B2f[1][kf] = fa; B2f[2][kf] = ft; B2f[3][kf] = fc;
        }

        // ===== layer 2 (128 -> 128): A=W2^T from LDS, B=activations; epilogue shuffles into B3 frags =====
        u32x4 B3f[4][4];
#pragma unroll
        for (int s = 0; s < 4; s++)
#pragma unroll
            for (int kf = 0; kf < 4; kf++)
                B3f[s][kf] = (u32x4){0u, 0u, 0u, 0u};

#pragma unroll
        for (int nt = 0; nt < 8; nt++) {
            const u16* arow = &w2t[(nt * 16 + e) * KP];
            f32x4 bia = *(const f32x4*)&b2s[nt * 16 + q * 4];
            f32x4 av = bia;
            f32x4 aa = {0.f, 0.f, 0.f, 0.f};
            f32x4 at_ = {0.f, 0.f, 0.f, 0.f};
            f32x4 ac = {0.f, 0.f, 0.f, 0.f};
#pragma unroll
            for (int kf = 0; kf < 4; kf++) {
                short8 A = *(const short8*)&arow[kf * 32 + q * 8];
                MFMA16(av, A, AS_S8(B2f[0][kf]));
                MFMA16(aa, A, AS_S8(B2f[1][kf]));
                MFMA16(at_, A, AS_S8(B2f[2][kf]));
                MFMA16(ac, A, AS_S8(B2f[3][kf]));
            }
            // chain rule in C-layout (rows = features nt*16+q*4+r, col = example e)
            float h_[4], na_[4], nv_[4], nc_[4];
#pragma unroll
            for (int r = 0; r < 4; r++) {
                float h = tanh_fast(av[r]);
                float g = 1.0f - h * h;
                h_[r] = h;
                na_[r] = g * aa[r];
                nv_[r] = g * at_[r];
                nc_[r] = g * ac[r] - 2.0f * h * g * aa[r] * aa[r];
            }
            u32 lo0 = pkbf(h_[0], h_[1]), hi0 = pkbf(h_[2], h_[3]);
            u32 lo1 = pkbf(na_[0], na_[1]), hi1 = pkbf(na_[2], na_[3]);
            u32 lo2 = pkbf(nv_[0], nv_[1]), hi2 = pkbf(nv_[2], nv_[3]);
            u32 lo3 = pkbf(nc_[0], nc_[1]), hi3 = pkbf(nc_[2], nc_[3]);
            // cross-lane transform: C-layout -> next-layer B-frag (same example column)
            u32x4 c0 = { (u32)__shfl((int)lo0, srcA), (u32)__shfl((int)hi0, srcA),
                         (u32)__shfl((int)lo0, srcB), (u32)__shfl((int)hi0, srcB) };
            u32x4 c1 = { (u32)__shfl((int)lo1, srcA), (u32)__shfl((int)hi1, srcA),
                         (u32)__shfl((int)lo1, srcB), (u32)__shfl((int)hi1, srcB) };
            u32x4 c2 = { (u32)__shfl((int)lo2, srcA), (u32)__shfl((int)hi2, srcA),
                         (u32)__shfl((int)lo2, srcB), (u32)__shfl((int)hi2, srcB) };
            u32x4 c3 = { (u32)__shfl((int)lo3, srcA), (u32)__shfl((int)hi3, srcA),
                         (u32)__shfl((int)lo3, srcB), (u32)__shfl((int)hi3, srcB) };
            const bool take = (hiHalf == (nt & 1));
            const int kf = nt >> 1;
            B3f[0][kf] = take ? c0 : B3f[0][kf];
            B3f[1][kf] = take ? c1 : B3f[1][kf];
            B3f[2][kf] = take ? c2 : B3f[2][kf];
            B3f[3][kf] = take ? c3 : B3f[3][kf];
        }

        // ===== layer 3 (128 -> 64) + layer 4 (64 -> 1), fused =====
        float sT = 0.f, sA = 0.f, sTt = 0.f, sC = 0.f;
#pragma unroll
        for (int nt3 = 0; nt3 < 4; nt3++) {
            const u16* arow = &w3t[(nt3 * 16 + e) * KP];
            f32x4 bia = *(const f32x4*)&b3s[nt3 * 16 + q * 4];
            f32x4 v3 = bia;
            f32x4 a3 = {0.f, 0.f, 0.f, 0.f};
            f32x4 t3 = {0.f, 0.f, 0.f, 0.f};
            f32x4 c3 = {0.f, 0.f, 0.f, 0.f};
#pragma unroll
            for (int kf = 0; kf < 4; kf++) {
                short8 A = *(const short8*)&arow[kf * 32 + q * 8];
                MFMA16(v3, A, AS_S8(B3f[0][kf]));
                MFMA16(a3, A, AS_S8(B3f[1][kf]));
                MFMA16(t3, A, AS_S8(B3f[2][kf]));
                MFMA16(c3, A, AS_S8(B3f[3][kf]));
            }
            f32x4 w4v = *(const f32x4*)&w4s[nt3 * 16 + q * 4];
#pragma unroll
            for (int r = 0; r < 4; r++) {
                float h = tanh_fast(v3[r]);
                float g = 1.0f - h * h;
                float wr = w4v[r];
                sT = fmaf(h, wr, sT);
                sA = fmaf(g * a3[r], wr, sA);
                sTt = fmaf(g * t3[r], wr, sTt);
                sC = fmaf(g * c3[r] - 2.0f * h * g * a3[r] * a3[r], wr, sC);
            }
        }
        // reduce across the 4 q-groups (features are q-distributed)
        sT += __shfl_xor(sT, 16);  sT += __shfl_xor(sT, 32);
        sA += __shfl_xor(sA, 16);  sA += __shfl_xor(sA, 32);
        sTt += __shfl_xor(sTt, 16); sTt += __shfl_xor(sTt, 32);
        sC += __shfl_xor(sC, 16);  sC += __shfl_xor(sC, 32);

        if (lane < 16) {
            *(float4*)(out + 4 * (size_t)(gbase + lane)) =
                make_float4(sT + b4v, sA, sTt, sC);
        }
    }
}

extern "C" void kernel_launch(void* const* d_in, const int* in_sizes, int n_in,
                              void* d_out, int out_size, void* d_ws, size_t ws_size,
                              hipStream_t stream) {
    const float* x  = (const float*)d_in[0];
    const float* W1 = (const float*)d_in[1];
    const float* b1 = (const float*)d_in[2];
    const float* W2 = (const float*)d_in[3];
    const float* b2 = (const float*)d_in[4];
    const float* W3 = (const float*)d_in[5];
    const float* b3 = (const float*)d_in[6];
    const float* W4 = (const float*)d_in[7];
    const float* b4 = (const float*)d_in[8];
    float* out = (float*)d_out;
    int N = in_sizes[0] / 3;

    hipLaunchKernelGGL(pinn_mfma4, dim3(GRID), dim3(BLOCK), 0, stream,
                       x, W1, b1, W2, b2, W3, b3, W4, b4, out, N);
}

// Round 5
// 550.260 us; speedup vs baseline: 1.3937x; 1.0108x over previous
//
#include <hip/hip_runtime.h>

typedef __attribute__((ext_vector_type(8))) short short8;
typedef __attribute__((ext_vector_type(4))) float f32x4;
typedef __attribute__((ext_vector_type(4))) unsigned int u32x4;
typedef unsigned short u16;
typedef unsigned int u32;

#define BLOCK 256
#define WPB 4
#define GRID 512
#define KP 136   // padded LDS row stride (shorts)

__device__ __forceinline__ float tanh_fast(float x) {
    float e = __expf(2.0f * x);
    return 1.0f - 2.0f / (e + 1.0f);   // exact at +-inf
}
__device__ __forceinline__ u16 f2bf(float f) {   // RNE (weights staging, once)
    u32 u = __float_as_uint(f);
    return (u16)((u + 0x7fffu + ((u >> 16) & 1u)) >> 16);
}
__device__ __forceinline__ u32 pkbf(float a, float b) {  // round-half-up pack: a->low, b->high
    u32 ua = (__float_as_uint(a) + 0x8000u) >> 16;
    u32 ub = (__float_as_uint(b) + 0x8000u) & 0xffff0000u;
    return ub | ua;
}
#define MFMA16(acc, a, b) acc = __builtin_amdgcn_mfma_f32_16x16x32_bf16(a, b, acc, 0, 0, 0)
#define AS_S8(v) __builtin_bit_cast(short8, v)

// NOTE: no min-waves/EU arg. On gfx950 the VGPR/AGPR file is unified and the
// launch-bounds cap applies to the COMBINED budget; (256,2) capped it at 256,
// the compiler split 128 arch + 128 acc and spilled ~1 GB/dispatch to scratch
// (R3/R4 evidence: reported VGPR_Count == cap/2 both times). Uncapped -> 512.
__global__ __launch_bounds__(BLOCK) void pinn_mfma5(
    const float* __restrict__ x,
    const float* __restrict__ W1, const float* __restrict__ b1,
    const float* __restrict__ W2, const float* __restrict__ b2,
    const float* __restrict__ W3, const float* __restrict__ b3,
    const float* __restrict__ W4, const float* __restrict__ b4,
    float* __restrict__ out, int N)
{
    // weights only: 55.3 KB
    __shared__ __align__(16) u16 w2t[128 * KP];    // W2^T: [n][k]
    __shared__ __align__(16) u16 w3t[64 * KP];     // W3^T: [n][k]
    __shared__ __align__(16) float4 w1s[128];      // q-transposed: slot kf*32+j*4+q holds feature kf*32+q*8+j
    __shared__ __align__(16) float b2s[128];
    __shared__ __align__(16) float b3s[64];
    __shared__ __align__(16) float w4s[64];

    for (int i = threadIdx.x; i < 128 * 128; i += BLOCK) {
        int k = i >> 7, n = i & 127;
        w2t[n * KP + k] = f2bf(W2[i]);
    }
    for (int i = threadIdx.x; i < 128 * 64; i += BLOCK) {
        int k = i >> 6, n = i & 63;
        w3t[n * KP + k] = f2bf(W3[i]);
    }
    for (int i = threadIdx.x; i < 128; i += BLOCK) {
        int kf = i >> 5, j = (i >> 2) & 7, qq = i & 3;
        int f = kf * 32 + qq * 8 + j;
        w1s[i] = make_float4(W1[f], W1[128 + f], W1[256 + f], b1[f]);
        b2s[i] = b2[i];
    }
    for (int i = threadIdx.x; i < 64; i += BLOCK) { b3s[i] = b3[i]; w4s[i] = W4[i]; }
    __syncthreads();

    const int lane = threadIdx.x & 63;
    const int wv = threadIdx.x >> 6;
    const int q = lane >> 4;       // k-quad for A/B frags
    const int e = lane & 15;       // example column
    const int srcA = (((q * 2) & 3) << 4) | e;       // transform source lanes (nt-independent)
    const int srcB = (((q * 2 + 1) & 3) << 4) | e;
    const int hiHalf = q >> 1;
    const float b4v = b4[0];

    const int ntiles = N >> 4;
    const int gw = blockIdx.x * WPB + wv;
    const int nw = GRID * WPB;

    for (int tile = gw; tile < ntiles; tile += nw) {
        const int gbase = tile << 4;
        const float* xp = x + 3 * (size_t)(gbase + e);
        float x0 = xp[0], x1 = xp[1], x2 = xp[2];

        // ===== layer 1 (3 -> 128): produce B2 frags directly in registers =====
        u32x4 B2f[4][4];   // [stream][kf]
#pragma unroll
        for (int kf = 0; kf < 4; kf++) {
            u32x4 fv, fa, ft, fc;
#pragma unroll
            for (int jp = 0; jp < 4; jp++) {
                float hv[2], av_[2], tv[2], cv[2];
#pragma unroll
                for (int u = 0; u < 2; u++) {
                    float4 w = w1s[kf * 32 + (jp * 2 + u) * 4 + q];  // {W1[0][f],W1[1][f],W1[2][f],b1[f]}
                    float z = fmaf(x0, w.x, fmaf(x1, w.y, fmaf(x2, w.z, w.w)));
                    float h = tanh_fast(z);
                    float g = 1.0f - h * h;
                    hv[u] = h;
                    av_[u] = g * w.x;
                    tv[u] = g * w.y;
                    cv[u] = -2.0f * h * g * w.x * w.x;
                }
                fv[jp] = pkbf(hv[0], hv[1]);
                fa[jp] = pkbf(av_[0], av_[1]);
                ft[jp] = pkbf(tv[0], tv[1]);
                fc[jp] = pkbf(cv[0], cv[1]);
            }
            B2f[0][kf] = fv; B2f[1][kf] = fa; B2f[2][kf] = ft; B2f[3][kf] = fc;
        }

        // ===== layer 2 (128 -> 128): A=W2^T from LDS, B=activations; epilogue shuffles into B3 frags =====
        u32x4 B3f[4][4];
#pragma unroll
        for (int s = 0; s < 4; s++)
#pragma unroll
            for (int kf = 0; kf < 4; kf++)
                B3f[s][kf] = (u32x4){0u, 0u, 0u, 0u};

#pragma unroll
        for (int nt = 0; nt < 8; nt++) {
            const u16* arow = &w2t[(nt * 16 + e) * KP];
            f32x4 bia = *(const f32x4*)&b2s[nt * 16 + q * 4];
            f32x4 av = bia;
            f32x4 aa = {0.f, 0.f, 0.f, 0.f};
            f32x4 at_ = {0.f, 0.f, 0.f, 0.f};
            f32x4 ac = {0.f, 0.f, 0.f, 0.f};
#pragma unroll
            for (int kf = 0; kf < 4; kf++) {
                short8 A = *(const short8*)&arow[kf * 32 + q * 8];
                MFMA16(av, A, AS_S8(B2f[0][kf]));
                MFMA16(aa, A, AS_S8(B2f[1][kf]));
                MFMA16(at_, A, AS_S8(B2f[2][kf]));
                MFMA16(ac, A, AS_S8(B2f[3][kf]));
            }
            // chain rule in C-layout (rows = features nt*16+q*4+r, col = example e)
            float h_[4], na_[4], nv_[4], nc_[4];
#pragma unroll
            for (int r = 0; r < 4; r++) {
                float h = tanh_fast(av[r]);
                float g = 1.0f - h * h;
                h_[r] = h;
                na_[r] = g * aa[r];
                nv_[r] = g * at_[r];
                nc_[r] = g * ac[r] - 2.0f * h * g * aa[r] * aa[r];
            }
            u32 lo0 = pkbf(h_[0], h_[1]), hi0 = pkbf(h_[2], h_[3]);
            u32 lo1 = pkbf(na_[0], na_[1]), hi1 = pkbf(na_[2], na_[3]);
            u32 lo2 = pkbf(nv_[0], nv_[1]), hi2 = pkbf(nv_[2], nv_[3]);
            u32 lo3 = pkbf(nc_[0], nc_[1]), hi3 = pkbf(nc_[2], nc_[3]);
            // cross-lane transform: C-layout -> next-layer B-frag (same example column)
            u32x4 c0 = { (u32)__shfl((int)lo0, srcA), (u32)__shfl((int)hi0, srcA),
                         (u32)__shfl((int)lo0, srcB), (u32)__shfl((int)hi0, srcB) };
            u32x4 c1 = { (u32)__shfl((int)lo1, srcA), (u32)__shfl((int)hi1, srcA),
                         (u32)__shfl((int)lo1, srcB), (u32)__shfl((int)hi1, srcB) };
            u32x4 c2 = { (u32)__shfl((int)lo2, srcA), (u32)__shfl((int)hi2, srcA),
                         (u32)__shfl((int)lo2, srcB), (u32)__shfl((int)hi2, srcB) };
            u32x4 c3 = { (u32)__shfl((int)lo3, srcA), (u32)__shfl((int)hi3, srcA),
                         (u32)__shfl((int)lo3, srcB), (u32)__shfl((int)hi3, srcB) };
            const bool take = (hiHalf == (nt & 1));
            const int kf = nt >> 1;
            B3f[0][kf] = take ? c0 : B3f[0][kf];
            B3f[1][kf] = take ? c1 : B3f[1][kf];
            B3f[2][kf] = take ? c2 : B3f[2][kf];
            B3f[3][kf] = take ? c3 : B3f[3][kf];
        }

        // ===== layer 3 (128 -> 64) + layer 4 (64 -> 1), fused =====
        float sT = 0.f, sA = 0.f, sTt = 0.f, sC = 0.f;
#pragma unroll
        for (int nt3 = 0; nt3 < 4; nt3++) {
            const u16* arow = &w3t[(nt3 * 16 + e) * KP];
            f32x4 bia = *(const f32x4*)&b3s[nt3 * 16 + q * 4];
            f32x4 v3 = bia;
            f32x4 a3 = {0.f, 0.f, 0.f, 0.f};
            f32x4 t3 = {0.f, 0.f, 0.f, 0.f};
            f32x4 c3 = {0.f, 0.f, 0.f, 0.f};
#pragma unroll
            for (int kf = 0; kf < 4; kf++) {
                short8 A = *(const short8*)&arow[kf * 32 + q * 8];
                MFMA16(v3, A, AS_S8(B3f[0][kf]));
                MFMA16(a3, A, AS_S8(B3f[1][kf]));
                MFMA16(t3, A, AS_S8(B3f[2][kf]));
                MFMA16(c3, A, AS_S8(B3f[3][kf]));
            }
            f32x4 w4v = *(const f32x4*)&w4s[nt3 * 16 + q * 4];
#pragma unroll
            for (int r = 0; r < 4; r++) {
                float h = tanh_fast(v3[r]);
                float g = 1.0f - h * h;
                float wr = w4v[r];
                sT = fmaf(h, wr, sT);
                sA = fmaf(g * a3[r], wr, sA);
                sTt = fmaf(g * t3[r], wr, sTt);
                sC = fmaf(g * c3[r] - 2.0f * h * g * a3[r] * a3[r], wr, sC);
            }
        }
        // reduce across the 4 q-groups (features are q-distributed)
        sT += __shfl_xor(sT, 16);  sT += __shfl_xor(sT, 32);
        sA += __shfl_xor(sA, 16);  sA += __shfl_xor(sA, 32);
        sTt += __shfl_xor(sTt, 16); sTt += __shfl_xor(sTt, 32);
        sC += __shfl_xor(sC, 16);  sC += __shfl_xor(sC, 32);

        if (lane < 16) {
            *(float4*)(out + 4 * (size_t)(gbase + lane)) =
                make_float4(sT + b4v, sA, sTt, sC);
        }
    }
}

extern "C" void kernel_launch(void* const* d_in, const int* in_sizes, int n_in,
                              void* d_out, int out_size, void* d_ws, size_t ws_size,
                              hipStream_t stream) {
    const float* x  = (const float*)d_in[0];
    const float* W1 = (const float*)d_in[1];
    const float* b1 = (const float*)d_in[2];
    const float* W2 = (const float*)d_in[3];
    const float* b2 = (const float*)d_in[4];
    const float* W3 = (const float*)d_in[5];
    const float* b3 = (const float*)d_in[6];
    const float* W4 = (const float*)d_in[7];
    const float* b4 = (const float*)d_in[8];
    float* out = (float*)d_out;
    int N = in_sizes[0] / 3;

    hipLaunchKernelGGL(pinn_mfma5, dim3(GRID), dim3(BLOCK), 0, stream,
                       x, W1, b1, W2, b2, W3, b3, W4, b4, out, N);
}